// Round 2
// baseline (171.547 us; speedup 1.0000x reference)
//
#include <hip/hip_runtime.h>

#define D 256
#define H 8
#define B 32
#define S 1024
#define SCH 16      // s-chunks per batch
#define SCS 64      // s per chunk

#define NBLK 256    // == CU count: 1 block/CU => all co-resident, barrier-safe
#define NTHR 512    // 8 waves/block

// workspace layout (float offsets)
#define OFF_QK   0          // [H][D]               2048
#define OFF_SB   2048       // [H]                  8
#define OFF_ML   2056       // [B][SCH][H] float2   8192 floats
#define OFF_XWP  10248      // [B][SCH][H][D]       1048576
#define OFF_BAR  1058824    // int cnt, int gen (zeroed by hipMemsetAsync each replay)

// Sense-reversing grid barrier, AGENT (device) scope => coherent across XCDs.
// Spin cap guarantees termination even if co-residency were ever violated.
__device__ __forceinline__ void grid_barrier(int* cnt, int* gen) {
    __syncthreads();
    if (threadIdx.x == 0) {
        const int g = __hip_atomic_load(gen, __ATOMIC_RELAXED, __HIP_MEMORY_SCOPE_AGENT);
        const int v = __hip_atomic_fetch_add(cnt, 1, __ATOMIC_ACQ_REL, __HIP_MEMORY_SCOPE_AGENT);
        if (v == NBLK - 1) {
            __hip_atomic_store(cnt, 0, __ATOMIC_RELAXED, __HIP_MEMORY_SCOPE_AGENT);
            __hip_atomic_store(gen, g + 1, __ATOMIC_RELEASE, __HIP_MEMORY_SCOPE_AGENT);
        } else {
            int it = 0;
            while (__hip_atomic_load(gen, __ATOMIC_ACQUIRE, __HIP_MEMORY_SCOPE_AGENT) == g) {
                __builtin_amdgcn_s_sleep(2);
                if (++it > 4000000) break;   // failsafe: never hang the bench
            }
        }
    }
    __syncthreads();
}

__global__ void __launch_bounds__(NTHR, 2) k_mega(
        const float* __restrict__ x,  const float* __restrict__ Wk,
        const float* __restrict__ bk, const float* __restrict__ Wv,
        const float* __restrict__ bv, const float* __restrict__ query,
        const float* __restrict__ Wo, const float* __restrict__ bo,
        float* __restrict__ ws, float* __restrict__ out) {
    __shared__ float  qkL[H * D];        // 8 KB
    __shared__ float  sbL[H];
    __shared__ float  sc[2][SCS][H];     // 4 KB, one slab per 256-thread half
    __shared__ float2 mlL[2][SCH];
    __shared__ float  scaleL[2][SCH];
    __shared__ float  xwL[2][D / 2];
    __shared__ float  ppL[2][D];         // partial pooled per d-half

    float*  qk    = ws + OFF_QK;
    float*  sb    = ws + OFF_SB;
    float2* mlbuf = (float2*)(ws + OFF_ML);
    float*  xwp   = ws + OFF_XWP;
    int*    bar   = (int*)(ws + OFF_BAR);

    const int bid = blockIdx.x;
    const int t   = threadIdx.x;

    // ---------------- P0: qk (2048 dots), sb (8 dots), out = bo init ------
    {
        const int w    = t >> 6;             // wave id 0..7
        const int lane = t & 63;
        const int p    = bid * 8 + w;        // pair id 0..2047
        const int h    = p >> 8, k = p & 255;
        const float4 wv = *(const float4*)(Wk + (size_t)k * (D * H) + h * D + lane * 4);
        const float4 qv = *(const float4*)(query + h * D + lane * 4);
        float acc = wv.x * qv.x + wv.y * qv.y + wv.z * qv.z + wv.w * qv.w;
        #pragma unroll
        for (int m = 1; m < 64; m <<= 1) acc += __shfl_xor(acc, m);
        if (lane == 0) qk[h * D + k] = acc;
        if (bid < 8 && w == 0) {             // sb[h=bid], one wave
            const float4 bkv = *(const float4*)(bk + bid * D + lane * 4);
            const float4 qv2 = *(const float4*)(query + bid * D + lane * 4);
            float a2 = bkv.x * qv2.x + bkv.y * qv2.y + bkv.z * qv2.z + bkv.w * qv2.w;
            #pragma unroll
            for (int m = 1; m < 64; m <<= 1) a2 += __shfl_xor(a2, m);
            if (lane == 0) sb[bid] = a2;
        }
        if (bid < 16) {                      // out[0:32][0:256] = bo (poison-safe)
            const int idx = bid * NTHR + t;  // 0..8191 contiguous
            out[idx] = bo[idx & 255];
        }
    }
    grid_barrier(bar, bar + 1);

    // ---------------- P1: scores -> chunk softmax -> unnormalized sums ----
    // two (b,c) tasks per block, one per 256-thread half; qkL shared by both
    {
        const int half = t >> 8, tt = t & 255;
        const int task = bid * 2 + half;
        const int b = task >> 4, c = task & 15;
        const int s0 = c * SCS;
        {
            ((float4*)qkL)[t] = ((const float4*)qk)[t];   // 512 float4 = 2048 f
            if (t < H) sbL[t] = sb[t];
        }
        __syncthreads();

        // pass A: (sl = tt>>2: 64 s) x (dq = tt&3: 64 d), XOR-staggered j
        {
            const int sl = tt >> 2;
            const int dq = tt & 3;
            const int d0 = dq * 64;
            const float* xrow = x + ((size_t)(b * S + s0 + sl)) * D + d0;
            float accA[H] = {};
            #pragma unroll
            for (int j0 = 0; j0 < 16; j0++) {
                const int j = (j0 + dq * 4) & 15;
                const float4 xv = *(const float4*)(xrow + j * 4);
                #pragma unroll
                for (int hh = 0; hh < H; hh++) {
                    const float4 qv = *(const float4*)(&qkL[hh * D + d0 + j * 4]);
                    accA[hh] += xv.x * qv.x + xv.y * qv.y + xv.z * qv.z + xv.w * qv.w;
                }
            }
            #pragma unroll
            for (int hh = 0; hh < H; hh++) {
                accA[hh] += __shfl_xor(accA[hh], 1);
                accA[hh] += __shfl_xor(accA[hh], 2);
            }
            if (dq == 0) {
                #pragma unroll
                for (int hh = 0; hh < H; hh++)
                    sc[half][sl][hh] = accA[hh] + sbL[hh];
            }
        }
        __syncthreads();

        // chunk softmax over 64 s per head: (hh = tt>>5) x (u = tt&31)
        {
            const int hh = tt >> 5;
            const int u  = tt & 31;
            const float v0 = sc[half][u][hh], v1 = sc[half][u + 32][hh];
            float m = fmaxf(v0, v1);
            #pragma unroll
            for (int msk = 1; msk < 32; msk <<= 1) m = fmaxf(m, __shfl_xor(m, msk));
            const float e0 = __expf(v0 - m), e1 = __expf(v1 - m);
            float sum = e0 + e1;
            #pragma unroll
            for (int msk = 1; msk < 32; msk <<= 1) sum += __shfl_xor(sum, msk);
            sc[half][u][hh] = e0;
            sc[half][u + 32][hh] = e1;
            if (u == 0) mlbuf[((size_t)(b * SCH + c)) * H + hh] = make_float2(m, sum);
        }
        __syncthreads();

        // pass B: thread = d (tt); x re-read (L2), p broadcast from LDS
        {
            float acc2[H] = {};
            const float* xp = x + ((size_t)(b * S + s0)) * D + tt;
            #pragma unroll 4
            for (int s = 0; s < SCS; s++) {
                const float xv = xp[(size_t)s * D];
                const float4 pa = *(const float4*)(&sc[half][s][0]);
                const float4 pb = *(const float4*)(&sc[half][s][4]);
                acc2[0] += pa.x * xv; acc2[1] += pa.y * xv;
                acc2[2] += pa.z * xv; acc2[3] += pa.w * xv;
                acc2[4] += pb.x * xv; acc2[5] += pb.y * xv;
                acc2[6] += pb.z * xv; acc2[7] += pb.w * xv;
            }
            #pragma unroll
            for (int hh = 0; hh < H; hh++)
                xwp[(((size_t)(b * SCH + c)) * H + hh) * D + tt] = acc2[hh];
        }
    }
    grid_barrier(bar, bar + 1);

    // ---------------- P2: combine chunks + Wv GEMV + Wo GEMV -> out -------
    // block bid = (b,h); half = dh (split-K over d); k_out fused in.
    {
        const int half = t >> 8, tt = t & 255;
        const int dh = half;
        const int b = bid >> 3, h = bid & 7;
        if (tt < SCH) mlL[half][tt] = mlbuf[((size_t)(b * SCH + tt)) * H + h];
        __syncthreads();
        if (tt == 0) {
            float M = -1e30f;
            for (int cc = 0; cc < SCH; cc++) M = fmaxf(M, mlL[half][cc].x);
            float L = 0.f;
            for (int cc = 0; cc < SCH; cc++) L += mlL[half][cc].y * __expf(mlL[half][cc].x - M);
            const float invL = 1.f / L;
            for (int cc = 0; cc < SCH; cc++) scaleL[half][cc] = __expf(mlL[half][cc].x - M) * invL;
        }
        __syncthreads();
        if (tt < D / 2) {                    // combine chunks for this d-half
            const int d = dh * (D / 2) + tt;
            float acc = 0.f;
            #pragma unroll
            for (int cc = 0; cc < SCH; cc++)
                acc += xwp[(((size_t)(b * SCH + cc)) * H + h) * D + d] * scaleL[half][cc];
            xwL[half][tt] = acc;
        }
        __syncthreads();
        {                                    // Wv GEMV: partial pooled (this d-half)
            const float* wcol = Wv + (size_t)(dh * (D / 2)) * (D * H) + h * D + tt;
            float a2 = 0.f;
            #pragma unroll 8
            for (int d = 0; d < D / 2; d++)
                a2 += xwL[half][d] * wcol[(size_t)d * (D * H)];
            if (dh == 0) a2 += bv[h * D + tt];   // bv folded in exactly once
            ppL[half][tt] = a2;
        }
        __syncthreads();
        if (half == 0) ppL[0][tt] += ppL[1][tt]; // full pooled for (b,h)
        __syncthreads();
        {                                    // Wo GEMV, jj-range split by half
            const int j0 = half * 128;
            const float* wp = Wo + (size_t)(h * D + j0) * D + tt;
            float o = 0.f;
            #pragma unroll 8
            for (int jj = 0; jj < 128; jj++)
                o += ppL[0][j0 + jj] * wp[(size_t)jj * D];
            atomicAdd(out + (size_t)b * D + tt, o);
        }
    }
}

extern "C" void kernel_launch(void* const* d_in, const int* in_sizes, int n_in,
                              void* d_out, int out_size, void* d_ws, size_t ws_size,
                              hipStream_t stream) {
    const float* x     = (const float*)d_in[0];
    const float* Wk    = (const float*)d_in[1];
    const float* bk    = (const float*)d_in[2];
    const float* Wv    = (const float*)d_in[3];
    const float* bv    = (const float*)d_in[4];
    const float* query = (const float*)d_in[5];
    const float* Wo    = (const float*)d_in[6];
    const float* bo    = (const float*)d_in[7];
    float* out = (float*)d_out;
    float* ws  = (float*)d_ws;

    // zero the barrier state every replay (workspace is poisoned between iters)
    hipMemsetAsync((char*)d_ws + (size_t)OFF_BAR * sizeof(float), 0,
                   2 * sizeof(int), stream);
    k_mega<<<dim3(NBLK), dim3(NTHR), 0, stream>>>(
        x, Wk, bk, Wv, bv, query, Wo, bo, ws, out);
}

// Round 3
// 122.624 us; speedup vs baseline: 1.3990x; 1.3990x over previous
//
#include <hip/hip_runtime.h>

#define D 256
#define H 8
#define B 32
#define S 1024
#define SCH 64      // s-chunks per batch (16 s each) -> 2048 fused blocks
#define SCS 16      // s per chunk

// workspace layout (float offsets)
#define OFF_QK     0          // [H][D]                 2048
#define OFF_SB     2048       // [H]                    8
#define OFF_ML     2056       // [B][SCH][H] float2     32768 floats
#define OFF_XWP    34824      // [B][SCH][H][D]         4194304
#define OFF_POOLED 4229128    // [B][H*D]               65536
// total ~17.2 MB (ws is 256 MB)

// ---- qk[h][k] = Wk[k, h*D+:] . q[h]; sb[h] = bk_h . q[h];
// ---- inits: out = bo, pooled = bv. (verified round-0 body, unchanged)
__global__ void __launch_bounds__(256) k_prep(
        const float* __restrict__ Wk, const float* __restrict__ bk,
        const float* __restrict__ query, const float* __restrict__ bo,
        const float* __restrict__ bv,
        float* __restrict__ qk, float* __restrict__ sb,
        float* __restrict__ out, float* __restrict__ pooled) {
    __shared__ float red[256];
    const int h  = blockIdx.x >> 5;
    const int kc = blockIdx.x & 31;
    const int t  = threadIdx.x;
    const int kl = t >> 5;
    const int dq = t & 31;
    const int k  = kc * 8 + kl;
    const int d0 = dq * 8;
    const float* wrow = Wk + (size_t)k * (D * H) + h * D + d0;
    const float* qrow = query + h * D + d0;
    const float4 w0 = *(const float4*)(wrow);
    const float4 w1 = *(const float4*)(wrow + 4);
    const float4 q0 = *(const float4*)(qrow);
    const float4 q1 = *(const float4*)(qrow + 4);
    float acc = w0.x * q0.x + w0.y * q0.y + w0.z * q0.z + w0.w * q0.w
              + w1.x * q1.x + w1.y * q1.y + w1.z * q1.z + w1.w * q1.w;
    #pragma unroll
    for (int msk = 1; msk < 32; msk <<= 1) acc += __shfl_xor(acc, msk);
    if (dq == 0) qk[h * D + k] = acc;
    if (kc == 0) {                          // block-uniform
        red[t] = bk[h * D + t] * query[h * D + t];
        __syncthreads();
        for (int st = 128; st > 0; st >>= 1) {
            if (t < st) red[t] += red[t + st];
            __syncthreads();
        }
        if (t == 0) sb[h] = red[0];
    }
    pooled[(size_t)kc * (D * H) + h * D + t] = bv[h * D + t];
    if (h == 0) out[(size_t)kc * D + t] = bo[t];
}

// ---- One (b, chunk of 16 s): scores -> chunk softmax (m,l) -> unnormalized
// weighted sums. grid = B*SCH = 2048 blocks, 256 thr (8 blocks/CU).
__global__ void __launch_bounds__(256, 6) k_fused(
        const float* __restrict__ x, const float* __restrict__ qk,
        const float* __restrict__ sb, float* __restrict__ xwp,
        float2* __restrict__ mlbuf) {
    const int b  = blockIdx.x >> 6;
    const int c  = blockIdx.x & 63;
    const int s0 = c * SCS;
    const int t  = threadIdx.x;
    __shared__ float qkL[H * D];            // 8 KB
    __shared__ float sbL[H];
    __shared__ float sc[SCS][H];            // 512 B
    {
        float4* q4 = (float4*)qkL;
        q4[t]       = ((const float4*)qk)[t];
        q4[t + 256] = ((const float4*)qk)[t + 256];
        if (t < H) sbL[t] = sb[t];
    }
    __syncthreads();

    // pass A: thread = (sl = t>>4: 16 s) x (dq = t&15: 16 d's at d0=dq*16).
    // XOR-staggered 16B sub-offset: lane dq reads its 4 float4s in rotated
    // order -> qkL bank spread <=4-way; x addresses rotate identically.
    {
        const int sl = t >> 4;
        const int dq = t & 15;
        const int d0 = dq * 16;
        const float* xrow = x + ((size_t)(b * S + s0 + sl)) * D + d0;
        const int o0 = ((dq    ) & 3) * 4;
        const int o1 = ((dq + 1) & 3) * 4;
        const int o2 = ((dq + 2) & 3) * 4;
        const int o3 = ((dq + 3) & 3) * 4;
        const float4 xa = *(const float4*)(xrow + o0);
        const float4 xb = *(const float4*)(xrow + o1);
        const float4 xc = *(const float4*)(xrow + o2);
        const float4 xd = *(const float4*)(xrow + o3);
        float accA[H] = {};
        #pragma unroll
        for (int hh = 0; hh < H; hh++) {
            const float* qb = &qkL[hh * D + d0];
            const float4 qa = *(const float4*)(qb + o0);
            const float4 q1 = *(const float4*)(qb + o1);
            const float4 q2 = *(const float4*)(qb + o2);
            const float4 q3 = *(const float4*)(qb + o3);
            accA[hh] = xa.x * qa.x + xa.y * qa.y + xa.z * qa.z + xa.w * qa.w
                     + xb.x * q1.x + xb.y * q1.y + xb.z * q1.z + xb.w * q1.w
                     + xc.x * q2.x + xc.y * q2.y + xc.z * q2.z + xc.w * q2.w
                     + xd.x * q3.x + xd.y * q3.y + xd.z * q3.z + xd.w * q3.w;
        }
        #pragma unroll
        for (int hh = 0; hh < H; hh++) {
            accA[hh] += __shfl_xor(accA[hh], 1);
            accA[hh] += __shfl_xor(accA[hh], 2);
            accA[hh] += __shfl_xor(accA[hh], 4);
            accA[hh] += __shfl_xor(accA[hh], 8);
        }
        if (dq == 0) {
            #pragma unroll
            for (int hh = 0; hh < H; hh++)
                sc[sl][hh] = accA[hh] + sbL[hh];
        }
    }
    __syncthreads();

    // chunk softmax over 16 s per head: threads 0..127 = (hh = t>>4, u = t&15)
    if (t < 128) {
        const int hh = t >> 4;
        const int u  = t & 15;
        const float v = sc[u][hh];
        float m = v;
        #pragma unroll
        for (int msk = 1; msk < 16; msk <<= 1) m = fmaxf(m, __shfl_xor(m, msk));
        const float e = __expf(v - m);
        float sum = e;
        #pragma unroll
        for (int msk = 1; msk < 16; msk <<= 1) sum += __shfl_xor(sum, msk);
        sc[u][hh] = e;
        if (u == 0) mlbuf[((size_t)(b * SCH + c)) * H + hh] = make_float2(m, sum);
    }
    __syncthreads();

    // pass B: thread = d (t); x rows L1-hot from pass A, p broadcast from LDS.
    {
        float acc2[H] = {};
        const float* xp = x + ((size_t)(b * S + s0)) * D + t;
        #pragma unroll
        for (int s = 0; s < SCS; s++) {
            const float xv = xp[(size_t)s * D];
            const float4 pa = *(const float4*)(&sc[s][0]);
            const float4 pb = *(const float4*)(&sc[s][4]);
            acc2[0] += pa.x * xv; acc2[1] += pa.y * xv;
            acc2[2] += pa.z * xv; acc2[3] += pa.w * xv;
            acc2[4] += pb.x * xv; acc2[5] += pb.y * xv;
            acc2[6] += pb.z * xv; acc2[7] += pb.w * xv;
        }
        #pragma unroll
        for (int hh = 0; hh < H; hh++)
            xwp[(((size_t)(b * SCH + c)) * H + hh) * D + t] = acc2[hh];
    }
}

// ---- combine 64 chunks (scale exp(m_c-M)/L) + pooled GEMV vs Wv, split over
// d-halves. grid = B*H*2 = 512 blocks; atomicAdd into bv-initialized pooled.
__global__ void __launch_bounds__(256) k_pooled(
        const float* __restrict__ xwp, const float2* __restrict__ mlbuf,
        const float* __restrict__ Wv, float* __restrict__ pooled) {
    const int blk = blockIdx.x;
    const int bh  = blk >> 1;
    const int dh  = blk & 1;                // d-half
    const int b = bh >> 3, h = bh & 7;
    const int j = threadIdx.x;
    __shared__ float xwL[D / 2];
    __shared__ float scaleL[SCH];
    if (j < SCH) {                          // wave-parallel M, L, scales
        const float2 ml = mlbuf[((size_t)(b * SCH + j)) * H + h];
        float M = ml.x;
        #pragma unroll
        for (int msk = 1; msk < 64; msk <<= 1) M = fmaxf(M, __shfl_xor(M, msk));
        const float p = __expf(ml.x - M);
        float L = ml.y * p;
        #pragma unroll
        for (int msk = 1; msk < 64; msk <<= 1) L += __shfl_xor(L, msk);
        scaleL[j] = p / L;
    }
    __syncthreads();
    if (j < D / 2) {
        const int d = dh * (D / 2) + j;
        float acc = 0.f;
        #pragma unroll 8
        for (int cc = 0; cc < SCH; cc++)
            acc += xwp[(((size_t)(b * SCH + cc)) * H + h) * D + d] * scaleL[cc];
        xwL[j] = acc;
    }
    __syncthreads();
    const float* wcol = Wv + (size_t)(dh * (D / 2)) * (D * H) + h * D + j;
    float a2 = 0.f;
    #pragma unroll 8
    for (int d = 0; d < D / 2; d++)
        a2 += xwL[d] * wcol[(size_t)d * (D * H)];
    atomicAdd(pooled + (size_t)b * (D * H) + h * D + j, a2);
}

// ---- out[b,j] += sum_{k in chunk} pooled[b,k]*Wo[k,j]; out pre-init to bo.
__global__ void __launch_bounds__(256) k_out(
        const float* __restrict__ pooled, const float* __restrict__ Wo,
        float* __restrict__ out) {
    const int b  = blockIdx.x >> 4;
    const int kc = blockIdx.x & 15;
    const int j  = threadIdx.x;
    __shared__ float pL[128];
    if (j < 128) pL[j] = pooled[(size_t)b * (D * H) + kc * 128 + j];
    __syncthreads();
    const float* wp = Wo + (size_t)(kc * 128) * D + j;
    float acc = 0.f;
    #pragma unroll 8
    for (int cc = 0; cc < 128; cc++)
        acc += pL[cc] * wp[(size_t)cc * D];
    atomicAdd(out + (size_t)b * D + j, acc);
}

extern "C" void kernel_launch(void* const* d_in, const int* in_sizes, int n_in,
                              void* d_out, int out_size, void* d_ws, size_t ws_size,
                              hipStream_t stream) {
    const float* x     = (const float*)d_in[0];
    const float* Wk    = (const float*)d_in[1];
    const float* bk    = (const float*)d_in[2];
    const float* Wv    = (const float*)d_in[3];
    const float* bv    = (const float*)d_in[4];
    const float* query = (const float*)d_in[5];
    const float* Wo    = (const float*)d_in[6];
    const float* bo    = (const float*)d_in[7];
    float* out = (float*)d_out;
    float* ws  = (float*)d_ws;

    float*  qk     = ws + OFF_QK;
    float*  sb     = ws + OFF_SB;
    float2* mlbuf  = (float2*)(ws + OFF_ML);
    float*  xwp    = ws + OFF_XWP;
    float*  pooled = ws + OFF_POOLED;

    k_prep<<<dim3(H * 32), dim3(256), 0, stream>>>(Wk, bk, query, bo, bv, qk, sb, out, pooled);
    k_fused<<<dim3(B * SCH), dim3(256), 0, stream>>>(x, qk, sb, xwp, mlbuf);
    k_pooled<<<dim3(B * H * 2), dim3(256), 0, stream>>>(xwp, mlbuf, Wv, pooled);
    k_out<<<dim3(B * 16), dim3(256), 0, stream>>>(pooled, Wo, out);
}

// Round 4
// 118.456 us; speedup vs baseline: 1.4482x; 1.0352x over previous
//
#include <hip/hip_runtime.h>

#define D 256
#define H 8
#define B 32
#define S 1024
#define SCH 32      // s-chunks per batch (32 s each) -> 1024 fused blocks
#define SCS 32      // s per chunk

// workspace layout (float offsets)
#define OFF_QK   0          // [H][D]                    2048
#define OFF_SB   2048       // [H]                       8
#define OFF_ML   2056       // [B][H][SCH] float2        16384 floats
#define OFF_XWP  18440      // [B][H][SCH][D]            2097152 floats (8 MB)

// ---- qk[h][k] = Wk[k, h*D+:] . q[h]; sb[h] = bk_h . q[h]; out = bo init.
// (verified round-0 body, minus the now-deleted pooled init)
__global__ void __launch_bounds__(256) k_prep(
        const float* __restrict__ Wk, const float* __restrict__ bk,
        const float* __restrict__ query, const float* __restrict__ bo,
        float* __restrict__ qk, float* __restrict__ sb,
        float* __restrict__ out) {
    __shared__ float red[256];
    const int h  = blockIdx.x >> 5;
    const int kc = blockIdx.x & 31;
    const int t  = threadIdx.x;
    const int kl = t >> 5;
    const int dq = t & 31;
    const int k  = kc * 8 + kl;
    const int d0 = dq * 8;
    const float* wrow = Wk + (size_t)k * (D * H) + h * D + d0;
    const float* qrow = query + h * D + d0;
    const float4 w0 = *(const float4*)(wrow);
    const float4 w1 = *(const float4*)(wrow + 4);
    const float4 q0 = *(const float4*)(qrow);
    const float4 q1 = *(const float4*)(qrow + 4);
    float acc = w0.x * q0.x + w0.y * q0.y + w0.z * q0.z + w0.w * q0.w
              + w1.x * q1.x + w1.y * q1.y + w1.z * q1.z + w1.w * q1.w;
    #pragma unroll
    for (int msk = 1; msk < 32; msk <<= 1) acc += __shfl_xor(acc, msk);
    if (dq == 0) qk[h * D + k] = acc;
    if (kc == 0) {                          // block-uniform branch
        red[t] = bk[h * D + t] * query[h * D + t];
        __syncthreads();
        for (int st = 128; st > 0; st >>= 1) {
            if (t < st) red[t] += red[t + st];
            __syncthreads();
        }
        if (t == 0) sb[h] = red[0];
    }
    if (h == 0) out[(size_t)kc * D + t] = bo[t];
}

// ---- One (b, chunk of 32 s): scores -> chunk softmax (m,l) -> unnormalized
// weighted x-sums. grid = B*SCH = 1024 blocks (4/CU), 256 thr.
__global__ void __launch_bounds__(256, 4) k_fused(
        const float* __restrict__ x, const float* __restrict__ qk,
        const float* __restrict__ sb, float* __restrict__ xwp,
        float2* __restrict__ mlbuf) {
    const int b  = blockIdx.x >> 5;
    const int c  = blockIdx.x & 31;
    const int s0 = c * SCS;
    const int t  = threadIdx.x;
    __shared__ float qkL[H * D];            // 8 KB
    __shared__ float sbL[H];
    __shared__ float sc[SCS][H];            // 1 KB
    {
        float4* q4 = (float4*)qkL;
        q4[t]       = ((const float4*)qk)[t];
        q4[t + 256] = ((const float4*)qk)[t + 256];
        if (t < H) sbL[t] = sb[t];
    }
    __syncthreads();

    // pass A: thread = (sl = t>>3: 32 s) x (dq = t&7: 32 d's at d0=dq*32).
    // float4s visited in dq-rotated order: qkL reads are conflict-free across
    // dq (distinct 16B groups within the 128B bank wrap) and broadcast across
    // sl (same address); x loads cover the same 1KB row per 8 lanes.
    {
        const int sl = t >> 3;
        const int dq = t & 7;
        const int d0 = dq * 32;
        const float* xrow = x + ((size_t)(b * S + s0 + sl)) * D + d0;
        float4 xr[8];
        #pragma unroll
        for (int j0 = 0; j0 < 8; j0++) {
            const int je = (j0 + dq) & 7;
            xr[j0] = *(const float4*)(xrow + je * 4);
        }
        float accA[H];
        #pragma unroll
        for (int hh = 0; hh < H; hh++) {
            const float* qb = &qkL[hh * D + d0];
            float a = 0.f;
            #pragma unroll
            for (int j0 = 0; j0 < 8; j0++) {
                const int je = (j0 + dq) & 7;
                const float4 qv = *(const float4*)(qb + je * 4);
                a += xr[j0].x * qv.x + xr[j0].y * qv.y
                   + xr[j0].z * qv.z + xr[j0].w * qv.w;
            }
            accA[hh] = a;
        }
        #pragma unroll
        for (int hh = 0; hh < H; hh++) {
            accA[hh] += __shfl_xor(accA[hh], 1);
            accA[hh] += __shfl_xor(accA[hh], 2);
            accA[hh] += __shfl_xor(accA[hh], 4);
        }
        if (dq == 0) {
            #pragma unroll
            for (int hh = 0; hh < H; hh++)
                sc[sl][hh] = accA[hh] + sbL[hh];
        }
    }
    __syncthreads();

    // chunk softmax over 32 s per head: thread = (hh = t>>5, u = t&31);
    // masks 1..16 keep the reduction inside each 32-lane half.
    {
        const int hh = t >> 5;
        const int u  = t & 31;
        const float v = sc[u][hh];
        float m = v;
        #pragma unroll
        for (int msk = 1; msk < 32; msk <<= 1) m = fmaxf(m, __shfl_xor(m, msk));
        const float e = __expf(v - m);
        float sum = e;
        #pragma unroll
        for (int msk = 1; msk < 32; msk <<= 1) sum += __shfl_xor(sum, msk);
        sc[u][hh] = e;
        if (u == 0) mlbuf[((size_t)(b * H + hh)) * SCH + c] = make_float2(m, sum);
    }
    __syncthreads();

    // pass B: thread = d (t); x rows L1/L2-hot from pass A, p broadcast (LDS).
    {
        float acc2[H] = {};
        const float* xp = x + ((size_t)(b * S + s0)) * D + t;
        #pragma unroll 8
        for (int s = 0; s < SCS; s++) {
            const float xv = xp[(size_t)s * D];
            const float4 pa = *(const float4*)(&sc[s][0]);
            const float4 pb = *(const float4*)(&sc[s][4]);
            acc2[0] += pa.x * xv; acc2[1] += pa.y * xv;
            acc2[2] += pa.z * xv; acc2[3] += pa.w * xv;
            acc2[4] += pb.x * xv; acc2[5] += pb.y * xv;
            acc2[6] += pb.z * xv; acc2[7] += pb.w * xv;
        }
        #pragma unroll
        for (int hh = 0; hh < H; hh++)
            xwp[(((size_t)(b * H + hh)) * SCH + c) * D + t] = acc2[hh];
    }
}

// ---- combine chunks + Wv GEMV + bv + Wo GEMV -> atomicAdd(out).
// grid = B*H*2 = 512 blocks (b, h, dv-half), 256 thr. Replaces k_pooled+k_out.
__global__ void __launch_bounds__(256, 4) k_po(
        const float* __restrict__ xwp, const float2* __restrict__ mlbuf,
        const float* __restrict__ Wv, const float* __restrict__ bv,
        const float* __restrict__ Wo, float* __restrict__ out) {
    const int blk = blockIdx.x;
    const int dvh = blk & 1;                // dv-half of the Wv output
    const int bh  = blk >> 1;
    const int b = bh >> 3, h = bh & 7;
    const int t = threadIdx.x;
    __shared__ float scaleL[SCH];
    __shared__ float xwL[D];
    __shared__ float pp[256];
    __shared__ float pooledL[128];

    if (t < SCH) {                          // wave-parallel M, L, scales
        const float2 ml = mlbuf[((size_t)(b * H + h)) * SCH + t];
        float M = ml.x;
        #pragma unroll
        for (int msk = 1; msk < 32; msk <<= 1) M = fmaxf(M, __shfl_xor(M, msk));
        const float p = __expf(ml.x - M);
        float L = ml.y * p;
        #pragma unroll
        for (int msk = 1; msk < 32; msk <<= 1) L += __shfl_xor(L, msk);
        scaleL[t] = p / L;
    }
    __syncthreads();
    {                                       // combine 32 chunks: xw[d=t]
        const float* xp = xwp + ((size_t)(b * H + h)) * SCH * D + t;
        float acc = 0.f;
        #pragma unroll 8
        for (int cc = 0; cc < SCH; cc++)
            acc += xp[(size_t)cc * D] * scaleL[cc];
        xwL[t] = acc;
    }
    __syncthreads();
    {                                       // Wv GEMV (this dv-half), split-K x2
        const int kseg = t >> 7;
        const int dvl  = t & 127;
        const float* wp = Wv + (size_t)(kseg * 128) * (D * H) + h * D + dvh * 128 + dvl;
        float acc = 0.f;
        #pragma unroll 8
        for (int dd = 0; dd < 128; dd++)
            acc += xwL[kseg * 128 + dd] * wp[(size_t)dd * (D * H)];
        pp[t] = acc;
    }
    __syncthreads();
    if (t < 128) pooledL[t] = pp[t] + pp[t + 128] + bv[h * D + dvh * 128 + t];
    __syncthreads();
    {                                       // Wo GEMV over this dv-half
        const float* wo = Wo + (size_t)(h * D + dvh * 128) * D + t;
        float acc = 0.f;
        #pragma unroll 8
        for (int dv = 0; dv < 128; dv++)
            acc += pooledL[dv] * wo[(size_t)dv * D];
        atomicAdd(out + (size_t)b * D + t, acc);
    }
}

extern "C" void kernel_launch(void* const* d_in, const int* in_sizes, int n_in,
                              void* d_out, int out_size, void* d_ws, size_t ws_size,
                              hipStream_t stream) {
    const float* x     = (const float*)d_in[0];
    const float* Wk    = (const float*)d_in[1];
    const float* bk    = (const float*)d_in[2];
    const float* Wv    = (const float*)d_in[3];
    const float* bv    = (const float*)d_in[4];
    const float* query = (const float*)d_in[5];
    const float* Wo    = (const float*)d_in[6];
    const float* bo    = (const float*)d_in[7];
    float* out = (float*)d_out;
    float* ws  = (float*)d_ws;

    float*  qk    = ws + OFF_QK;
    float*  sb    = ws + OFF_SB;
    float2* mlbuf = (float2*)(ws + OFF_ML);
    float*  xwp   = ws + OFF_XWP;

    k_prep<<<dim3(H * 32), dim3(256), 0, stream>>>(Wk, bk, query, bo, qk, sb, out);
    k_fused<<<dim3(B * SCH), dim3(256), 0, stream>>>(x, qk, sb, xwp, mlbuf);
    k_po<<<dim3(B * H * 2), dim3(256), 0, stream>>>(xwp, mlbuf, Wv, bv, Wo, out);
}